// Round 1
// baseline (1769.088 us; speedup 1.0000x reference)
//
#include <hip/hip_runtime.h>

#define S 2048
#define DM 1024
#define NH 16
#define DK 64
#define BATCH 4

typedef float f4 __attribute__((ext_vector_type(4)));
typedef __bf16 bf16x8 __attribute__((ext_vector_type(8)));

#define MFMA(a, b, c) __builtin_amdgcn_mfma_f32_16x16x32_bf16(a, b, c, 0, 0, 0)

__device__ __forceinline__ unsigned short f2bf(float f) {
  union { float f; unsigned int u; } x; x.f = f;
  return (unsigned short)((x.u + 0x7FFFu + ((x.u >> 16) & 1u)) >> 16);
}

__device__ __forceinline__ unsigned int pack2(float a, float b) {
  return (unsigned int)f2bf(a) | ((unsigned int)f2bf(b) << 16);
}

// ---------------------------------------------------------------------------
// fp32 -> bf16 streaming convert, 8 elems/thread/iter
// ---------------------------------------------------------------------------
__global__ __launch_bounds__(256)
void cvt_kernel(const float* __restrict__ in, unsigned short* __restrict__ out,
                int n8) {
  int i = blockIdx.x * 256 + threadIdx.x;
  const int stride = gridDim.x * 256;
  for (; i < n8; i += stride) {
    const float4* p = (const float4*)in + 2 * (size_t)i;
    float4 a = p[0], b = p[1];
    uint4 o;
    o.x = pack2(a.x, a.y); o.y = pack2(a.z, a.w);
    o.z = pack2(b.x, b.y); o.w = pack2(b.z, b.w);
    ((uint4*)out)[i] = o;
  }
}

__device__ __forceinline__ void gl_lds16(const unsigned short* g,
                                         unsigned short* l) {
  __builtin_amdgcn_global_load_lds(
      (const __attribute__((address_space(1))) unsigned int*)g,
      (__attribute__((address_space(3))) unsigned int*)l, 16, 0, 0);
}

// ---------------------------------------------------------------------------
// Y[M,N] = Xb[M,K](bf16) @ Wb[N,K](bf16)^T (+ res fp32), out fp32 or bf16.
// m97 structure: 128x128 tile, BK=64, linear LDS, global_load_lds dwordx4,
// 2 barriers per K-step, 4 waves 2x2, 4x4 16x16x32 MFMA per wave.
// ---------------------------------------------------------------------------
template <bool OUT_BF16, bool RES>
__global__ __launch_bounds__(256)
void gemm_bf(const unsigned short* __restrict__ X,
             const unsigned short* __restrict__ W,
             const float* __restrict__ res, void* __restrict__ Yv,
             int M_, int N_, int K_) {
  __shared__ alignas(16) unsigned short As[128 * 64];
  __shared__ alignas(16) unsigned short Bs[128 * 64];

  const int tid = threadIdx.x;
  const int wid = tid >> 6, lane = tid & 63;
  const int g = lane >> 4, c = lane & 15;

  // XCD-bijective swizzle (gridDim.x % 8 == 0)
  const int nwg = gridDim.x;
  const int wg = blockIdx.x;
  const int lb = (wg & 7) * (nwg >> 3) + (wg >> 3);
  const int nbx = N_ >> 7;
  const int m0 = (lb / nbx) << 7, n0 = (lb % nbx) << 7;
  const int wm = (wid >> 1) * 64, wn = (wid & 1) * 64;

  // staging: per wave 32 rows of A and B, 4 calls x 8 rows (1 KB per call)
  const int lrow = lane >> 3;        // 0..7 (row within the 8-row chunk)
  const int lk = (lane & 7) * 8;     // bf16 col offset, 16B per lane
  const unsigned short* xa = X + (size_t)(m0 + wid * 32 + lrow) * K_ + lk;
  const unsigned short* wb = W + (size_t)(n0 + wid * 32 + lrow) * K_ + lk;
  unsigned short* asb = &As[(wid * 32) * 64];
  unsigned short* bsb = &Bs[(wid * 32) * 64];

  f4 acc[4][4];
#pragma unroll
  for (int i = 0; i < 4; i++)
#pragma unroll
    for (int j = 0; j < 4; j++) acc[i][j] = (f4){0.f, 0.f, 0.f, 0.f};

  for (int k0 = 0; k0 < K_; k0 += 64) {
#pragma unroll
    for (int j = 0; j < 4; j++) {
      gl_lds16(xa + (size_t)j * 8 * K_ + k0, asb + j * 8 * 64);
      gl_lds16(wb + (size_t)j * 8 * K_ + k0, bsb + j * 8 * 64);
    }
    __syncthreads();  // compiler drains vmcnt before barrier
#pragma unroll
    for (int ks = 0; ks < 2; ks++) {
      bf16x8 av[4], bv[4];
#pragma unroll
      for (int i = 0; i < 4; i++)
        av[i] = *(const bf16x8*)&As[(wm + i * 16 + c) * 64 + ks * 32 + g * 8];
#pragma unroll
      for (int j = 0; j < 4; j++)
        bv[j] = *(const bf16x8*)&Bs[(wn + j * 16 + c) * 64 + ks * 32 + g * 8];
#pragma unroll
      for (int i = 0; i < 4; i++)
#pragma unroll
        for (int j = 0; j < 4; j++) acc[i][j] = MFMA(av[i], bv[j], acc[i][j]);
    }
    __syncthreads();
  }

#pragma unroll
  for (int i = 0; i < 4; i++) {
#pragma unroll
    for (int j = 0; j < 4; j++) {
      const int row = m0 + wm + i * 16 + g * 4;
      const int col = n0 + wn + j * 16 + c;
#pragma unroll
      for (int r = 0; r < 4; r++) {
        size_t off = (size_t)(row + r) * N_ + col;
        float vv = acc[i][j][r];
        if constexpr (RES) vv += res[off];
        if constexpr (OUT_BF16)
          ((unsigned short*)Yv)[off] = f2bf(vv);
        else
          ((float*)Yv)[off] = vv;
      }
    }
  }
}

// ---------------------------------------------------------------------------
// V transpose write: paired ds_write_b32 (rows kpair,kpair+1 -> cols of Vt)
// ---------------------------------------------------------------------------
__device__ __forceinline__ void vwrite(unsigned short* VtBuf, int kpair,
                                       int dblk, uint4 r0, uint4 r1) {
  const int LDA = 72;
  unsigned int lo[4] = {r0.x, r0.y, r0.z, r0.w};
  unsigned int hi[4] = {r1.x, r1.y, r1.z, r1.w};
#pragma unroll
  for (int p = 0; p < 4; p++) {
    unsigned int w0 = (lo[p] & 0xFFFFu) | (hi[p] << 16);
    unsigned int w1 = (lo[p] >> 16) | (hi[p] & 0xFFFF0000u);
    *(unsigned int*)&VtBuf[(dblk + 2 * p) * LDA + kpair] = w0;
    *(unsigned int*)&VtBuf[(dblk + 2 * p + 1) * LDA + kpair] = w1;
  }
}

// ---------------------------------------------------------------------------
// Fused attention. Per workgroup = one (b, h, 64 q rows), 4 waves.
// Q in registers. K B-frags loaded DIRECTLY from global (L1/L2-resident;
// 16B/lane, 64B-chunk coalesced) -> pass 1 has NO LDS and NO barriers.
// Pass 2: V double-buffered in LDS (load-early/write-late), Ps wave-private
// (no barrier needed), ONE barrier per K-tile.  Ctx written as bf16.
// ---------------------------------------------------------------------------
__global__ __launch_bounds__(256)
void attn_kernel(const unsigned short* __restrict__ Qp,
                 const unsigned short* __restrict__ Kp,
                 const unsigned short* __restrict__ Vp,
                 float* __restrict__ attnOut,
                 unsigned short* __restrict__ ctxOut) {
  const int LDA = 72;  // 64 + 8 pad
  __shared__ alignas(16) unsigned short Qs[64 * LDA];
  __shared__ alignas(16) unsigned short Vt[2][64 * LDA];
  __shared__ alignas(16) unsigned short Ps[4][16 * LDA];

  const int tid = threadIdx.x;
  const int wid = tid >> 6, lane = tid & 63;
  const int g = lane >> 4, c = lane & 15;

  // XCD-bijective swizzle: each XCD gets 256 consecutive logical blocks
  // = 8 whole heads -> K/V of a head fetched into exactly one L2.
  const int wg = blockIdx.x;
  const int bid = (wg & 7) * (int)(gridDim.x >> 3) + (wg >> 3);
  const int qb = bid & 31;          // S/64 = 32 q-blocks
  const int h = (bid >> 5) & 15;
  const int b = bid >> 9;

  const size_t headOff = ((size_t)b * NH + h) * S * DK;
  const unsigned short* Qh = Qp + headOff;
  const unsigned short* Kh = Kp + headOff;
  const unsigned short* Vh = Vp + headOff;
  float* attnB = attnOut + (((size_t)b * NH + h) * S + (size_t)qb * 64) * S;

  // stage Q once
  const int srow = tid >> 2, sd = (tid & 3) * 16;
  {
    const unsigned short* src = Qh + (size_t)(qb * 64 + srow) * DK + sd;
    uint4 a = ((const uint4*)src)[0];
    uint4 bq = ((const uint4*)src)[1];
    ((uint4*)&Qs[srow * LDA + sd])[0] = a;
    ((uint4*)&Qs[srow * LDA + sd])[1] = bq;
  }
  __syncthreads();
  const bf16x8 qa0 = *(const bf16x8*)&Qs[(wid * 16 + c) * LDA + g * 8];
  const bf16x8 qa1 = *(const bf16x8*)&Qs[(wid * 16 + c) * LDA + 32 + g * 8];

  float mrow[4], lrow[4];
#pragma unroll
  for (int r = 0; r < 4; r++) { mrow[r] = -1e30f; lrow[r] = 0.f; }
  const float scale = 0.125f;  // 1/sqrt(64)

  // ---- pass 1: row max + sumexp (no barriers, K from global) ----
  for (int kt = 0; kt < 32; kt++) {
    const unsigned short* kb = Kh + (size_t)kt * 64 * DK;
    f4 sf[4];
#pragma unroll
    for (int f = 0; f < 4; f++) {
      const unsigned short* kr = kb + (size_t)(f * 16 + c) * DK + g * 8;
      bf16x8 b0 = *(const bf16x8*)kr;
      bf16x8 b1 = *(const bf16x8*)(kr + 32);
      f4 s = (f4){0.f, 0.f, 0.f, 0.f};
      s = MFMA(qa0, b0, s);
      s = MFMA(qa1, b1, s);
      sf[f] = s * scale;
    }
    float tm[4], ps[4];
#pragma unroll
    for (int r = 0; r < 4; r++)
      tm[r] = fmaxf(fmaxf(sf[0][r], sf[1][r]), fmaxf(sf[2][r], sf[3][r]));
#pragma unroll
    for (int mask = 1; mask < 16; mask <<= 1)
#pragma unroll
      for (int r = 0; r < 4; r++)
        tm[r] = fmaxf(tm[r], __shfl_xor(tm[r], mask));
#pragma unroll
    for (int r = 0; r < 4; r++) {
      float nm = fmaxf(mrow[r], tm[r]);
      ps[r] = __expf(sf[0][r] - nm) + __expf(sf[1][r] - nm) +
              __expf(sf[2][r] - nm) + __expf(sf[3][r] - nm);
      lrow[r] = lrow[r] * __expf(mrow[r] - nm);
      mrow[r] = nm;
    }
#pragma unroll
    for (int mask = 1; mask < 16; mask <<= 1)
#pragma unroll
      for (int r = 0; r < 4; r++) ps[r] += __shfl_xor(ps[r], mask);
#pragma unroll
    for (int r = 0; r < 4; r++) lrow[r] += ps[r];
  }

  float rl[4];
#pragma unroll
  for (int r = 0; r < 4; r++) rl[r] = 1.f / lrow[r];

  f4 ctxv[4];
#pragma unroll
  for (int f = 0; f < 4; f++) ctxv[f] = (f4){0.f, 0.f, 0.f, 0.f};

  const int kpair = (tid & 31) * 2;   // k pair for V staging
  const int dblk = (tid >> 5) * 8;    // d block for V staging

  // prologue: stage V tile 0
  {
    const unsigned short* p0 = Vh + (size_t)kpair * DK + dblk;
    uint4 r0 = *(const uint4*)p0;
    uint4 r1 = *(const uint4*)(p0 + DK);
    vwrite(Vt[0], kpair, dblk, r0, r1);
  }
  __syncthreads();

  // ---- pass 2: attn out + ctx accumulate (1 barrier/iter) ----
  for (int kt = 0; kt < 32; kt++) {
    const int cur = kt & 1;
    const bool pre = (kt < 31);
    uint4 r0, r1;
    if (pre) {  // issue next V loads early (latency hides under compute)
      const unsigned short* p0 =
          Vh + (size_t)((kt + 1) * 64 + kpair) * DK + dblk;
      r0 = *(const uint4*)p0;
      r1 = *(const uint4*)(p0 + DK);
    }
    // scores recomputed with K from global (L1/L2 hit)
    const unsigned short* kb = Kh + (size_t)kt * 64 * DK;
    f4 pf[4];
#pragma unroll
    for (int f = 0; f < 4; f++) {
      const unsigned short* kr = kb + (size_t)(f * 16 + c) * DK + g * 8;
      bf16x8 b0 = *(const bf16x8*)kr;
      bf16x8 b1 = *(const bf16x8*)(kr + 32);
      f4 s = (f4){0.f, 0.f, 0.f, 0.f};
      s = MFMA(qa0, b0, s);
      s = MFMA(qa1, b1, s);
#pragma unroll
      for (int r = 0; r < 4; r++)
        pf[f][r] = __expf(s[r] * scale - mrow[r]) * rl[r];
    }
    // write normalized attn (fp32)
    float* ap = attnB + (size_t)(wid * 16 + g * 4) * S + kt * 64;
#pragma unroll
    for (int f = 0; f < 4; f++)
#pragma unroll
      for (int r = 0; r < 4; r++)
        ap[(size_t)r * S + f * 16 + c] = pf[f][r];
    // P -> LDS (wave-private; in-order DS pipe, no barrier needed)
#pragma unroll
    for (int f = 0; f < 4; f++)
#pragma unroll
      for (int r = 0; r < 4; r++)
        Ps[wid][(g * 4 + r) * LDA + f * 16 + c] = f2bf(pf[f][r]);
    bf16x8 pa0 = *(const bf16x8*)&Ps[wid][c * LDA + g * 8];
    bf16x8 pa1 = *(const bf16x8*)&Ps[wid][c * LDA + 32 + g * 8];
    // write next V tile into the other buffer (reads of it finished at the
    // barrier that ended the previous iteration)
    if (pre) vwrite(Vt[cur ^ 1], kpair, dblk, r0, r1);
    // PV from current V buffer
#pragma unroll
    for (int f = 0; f < 4; f++) {
      bf16x8 v0 = *(const bf16x8*)&Vt[cur][(f * 16 + c) * LDA + g * 8];
      bf16x8 v1 = *(const bf16x8*)&Vt[cur][(f * 16 + c) * LDA + 32 + g * 8];
      ctxv[f] = MFMA(pa0, v0, ctxv[f]);
      ctxv[f] = MFMA(pa1, v1, ctxv[f]);
    }
    __syncthreads();
  }

  // ctx -> bf16 [B,S,H*64] for the fc GEMM
  unsigned short* cp =
      ctxOut + ((size_t)b * S + (size_t)qb * 64 + wid * 16 + g * 4) * DM +
      h * 64;
#pragma unroll
  for (int f = 0; f < 4; f++)
#pragma unroll
    for (int r = 0; r < 4; r++)
      cp[(size_t)r * DM + f * 16 + c] = f2bf(ctxv[f][r]);
}

// ---------------------------------------------------------------------------
// In-place LayerNorm over rows of 1024.
// ---------------------------------------------------------------------------
__global__ __launch_bounds__(256)
void ln_kernel(float* __restrict__ X, const float* __restrict__ gamma,
               const float* __restrict__ beta) {
  __shared__ float ws[4], ws2[4];
  const int row = blockIdx.x;
  const int tid = threadIdx.x;
  const int wid = tid >> 6, lane = tid & 63;
  float* xp = X + (size_t)row * DM + tid * 4;
  float4 v = *(const float4*)xp;
  float s = v.x + v.y + v.z + v.w;
  float s2 = v.x * v.x + v.y * v.y + v.z * v.z + v.w * v.w;
#pragma unroll
  for (int m = 1; m < 64; m <<= 1) {
    s += __shfl_xor(s, m);
    s2 += __shfl_xor(s2, m);
  }
  if (lane == 0) { ws[wid] = s; ws2[wid] = s2; }
  __syncthreads();
  s = ws[0] + ws[1] + ws[2] + ws[3];
  s2 = ws2[0] + ws2[1] + ws2[2] + ws2[3];
  const float mean = s * (1.f / 1024.f);
  const float var = s2 * (1.f / 1024.f) - mean * mean;
  const float rstd = rsqrtf(var + 1e-6f);
  float4 gg = *(const float4*)(gamma + tid * 4);
  float4 bb = *(const float4*)(beta + tid * 4);
  float4 o;
  o.x = (v.x - mean) * rstd * gg.x + bb.x;
  o.y = (v.y - mean) * rstd * gg.y + bb.y;
  o.z = (v.z - mean) * rstd * gg.z + bb.z;
  o.w = (v.w - mean) * rstd * gg.w + bb.w;
  *(float4*)xp = o;
}

extern "C" void kernel_launch(void* const* d_in, const int* in_sizes, int n_in,
                              void* d_out, int out_size, void* d_ws,
                              size_t ws_size, hipStream_t stream) {
  const float* q = (const float*)d_in[0];
  const float* k = (const float*)d_in[1];
  const float* v = (const float*)d_in[2];
  const float* w_qs = (const float*)d_in[3];
  const float* w_ks = (const float*)d_in[4];
  const float* w_vs = (const float*)d_in[5];
  const float* w_fc = (const float*)d_in[6];
  const float* gamma = (const float*)d_in[7];
  const float* beta = (const float*)d_in[8];

  const size_t projN = (size_t)BATCH * S * DM;  // 8388608
  const size_t wN = (size_t)DM * DM;            // 1048576
  float* out = (float*)d_out;                   // x / LN region [B,S,1024]
  float* attnO = out + projN;                   // attn region [B,H,S,S]

  // workspace (bf16): Qp/Kp/Vp 16MB each, XB 16MB (X convert buf, then ctx),
  // 4 weight buffers 2MB each = 72 MB total
  unsigned short* Qp = (unsigned short*)d_ws;
  unsigned short* Kp = Qp + projN;
  unsigned short* Vp = Kp + projN;
  unsigned short* XB = Vp + projN;
  unsigned short* WQ = XB + projN;
  unsigned short* WK = WQ + wN;
  unsigned short* WV = WK + wN;
  unsigned short* WF = WV + wN;

  const int M = BATCH * S;                 // 8192
  const int GG = (M / 128) * (DM / 128);   // 512 blocks

  cvt_kernel<<<512, 256, 0, stream>>>(w_qs, WQ, (int)(wN / 8));
  cvt_kernel<<<512, 256, 0, stream>>>(w_ks, WK, (int)(wN / 8));
  cvt_kernel<<<512, 256, 0, stream>>>(w_vs, WV, (int)(wN / 8));
  cvt_kernel<<<512, 256, 0, stream>>>(w_fc, WF, (int)(wN / 8));

  cvt_kernel<<<2048, 256, 0, stream>>>(q, XB, (int)(projN / 8));
  gemm_bf<true, false><<<GG, 256, 0, stream>>>(XB, WQ, nullptr, Qp, M, DM, DM);
  cvt_kernel<<<2048, 256, 0, stream>>>(k, XB, (int)(projN / 8));
  gemm_bf<true, false><<<GG, 256, 0, stream>>>(XB, WK, nullptr, Kp, M, DM, DM);
  cvt_kernel<<<2048, 256, 0, stream>>>(v, XB, (int)(projN / 8));
  gemm_bf<true, false><<<GG, 256, 0, stream>>>(XB, WV, nullptr, Vp, M, DM, DM);

  attn_kernel<<<BATCH * NH * (S / 64), 256, 0, stream>>>(Qp, Kp, Vp, attnO, XB);

  gemm_bf<false, true><<<GG, 256, 0, stream>>>(XB, WF, q, out, M, DM, DM);
  ln_kernel<<<M, 256, 0, stream>>>(out, gamma, beta);
}